// Round 11
// baseline (1888.537 us; speedup 1.0000x reference)
//
#include <hip/hip_runtime.h>
#include <cstdint>
#include <cstddef>

#define SEQ 512
#define BATCH 256
#define SD 1024
#define OD 256
#define GB 16          // batches per group
#define NW 16          // workgroups per group

typedef short  bf8   __attribute__((ext_vector_type(8)));
typedef float  f32x4 __attribute__((ext_vector_type(4)));
typedef unsigned int u32x4 __attribute__((ext_vector_type(4)));

union BF16x8 { unsigned long long q[2]; u32x4 u; bf8 v; };

template <bool V> struct BoolC { static constexpr bool value = V; };

__device__ __forceinline__ unsigned short f2bf(float f) {
    unsigned u = __float_as_uint(f);
    u += 0x7FFFu + ((u >> 16) & 1u);      // round-to-nearest-even
    return (unsigned short)(u >> 16);
}

__device__ __forceinline__ float fast_tanh(float v) {
    float e = __expf(2.0f * v);
    return 1.0f - 2.0f / (e + 1.0f);
}

// agent-scope access: coherence point beyond L2, correct for ANY placement.
__device__ __forceinline__ bf8 t_load16_agent(const unsigned short* p) {
    BF16x8 u;
    unsigned long long* q = (unsigned long long*)p;
    u.q[0] = __hip_atomic_load(q,     __ATOMIC_RELAXED, __HIP_MEMORY_SCOPE_AGENT);
    u.q[1] = __hip_atomic_load(q + 1, __ATOMIC_RELAXED, __HIP_MEMORY_SCOPE_AGENT);
    return u.v;
}

// HW-verified facts driving this design:
//  (r6)  same-XCD groups: plain t-stores land in XCD L2; sc0 t-loads serve
//        from it. FETCH 219->89MB, WRITE 398->137MB.
//  (r7)  load-polling a hot line serves stale L1 forever -> flag POLLS must
//        be agent-scope loads.
//  (r8)  per-WG agent flags + throttled load poll: 1277us (best).
//  (r10) returning atomics execute at the MEMORY-SIDE point (WRITE_SIZE
//        +113MB) -> no L2-local flag primitive exists. Flags stay agent.
//
// Round-11: remove hops instead of shortening them.
//  - per-WAVE flags (64/group, own 64B line each). Producer wave: wave-level
//    s_waitcnt vmcnt(0) (drains ITS t-stores) + lane0 agent flag store.
//  - per-wave wait: lanes 0..15 poll the 16 producer-wave flags covering
//    this wave's K slice (WGs 4wid..4wid+3 x waves 0..3), s_sleep-throttled.
//  - ONE __syncthreads/step (red1 reduce). Buffer-reuse safety: union of the
//    4 waves' poll sets = all 64 group wave-flags >= i+1, made WG-uniform by
//    that barrier, and >= i-1 suffices for overwriting t_{i-2} (slack 2).
//  - red1/red2 parity ping-pong [2] makes the 1-barrier schedule race-free.
// Slow path (placement check fails): same protocol, agent-scope data ops.
__global__ void __launch_bounds__(256, 1)
rnn_persistent(const float* __restrict__ x,
               const float* __restrict__ h_init,
               const float* __restrict__ w_r,
               const float* __restrict__ b_r,
               const float* __restrict__ w_o,
               const float* __restrict__ b_o,
               float* __restrict__ out,
               unsigned char* __restrict__ ws)
{
    const int wg   = blockIdx.x;
    const int g    = wg & 15;      // group; members share blockIdx mod 8 -> same XCD (verified below)
    const int wi   = wg >> 4;      // 0..15 within group
    const int tid  = threadIdx.x;
    const int lane = tid & 63;
    const int wid  = tid >> 6;     // wave 0..3
    const int l15  = lane & 15;
    const int lq   = lane >> 4;    // k-quad 0..3

    // ws layout:
    //  [0, 64K)   wave flags: idx = g*64 + wi*4 + wv, addr = ws + idx*64
    //  [64K, 68K) startup blocks, 256B/group: +0 scnt | +4 sflag | +8 xarr[16]
    //  [68K, ...) t triple buffer: 3 x [256][1024] bf16
    unsigned* const myflag = (unsigned*)(ws + ((size_t)(g * 64 + wi * 4 + wid)) * 64);
    // lanes 0..15 poll producer-wave flags: idx = g*64 + 16*wid + lane
    const unsigned* const pollp = (const unsigned*)(ws + ((size_t)(g * 64 + 16 * wid + (lane & 15))) * 64);
    unsigned char* gctl = ws + 65536 + (size_t)g * 256;
    unsigned* scnt  = (unsigned*)(gctl + 0);
    unsigned* sflag = (unsigned*)(gctl + 4);
    unsigned* xarr  = (unsigned*)(gctl + 8);
    unsigned short* tbase = (unsigned short*)(ws + 69632);

    const int batch0 = g * GB;     // group's batch rows
    const int s0 = wi * 64;        // wg's state cols
    const int o0 = wi * 16;        // wg's output cols
    const int k0 = wid * 256;      // wave's K slice

    __shared__ float red1[2][4][4][4][68];  // [parity][wave][coltile][reg][lane] (+4 pad)
    __shared__ float red2[2][4][4][68];     // [parity][wave][reg][lane]
    __shared__ unsigned sx[16];

    // ---- preload w_r slice as B fragments in registers (128 VGPRs) ----
    bf8 B1[4][8];
#pragma unroll
    for (int ct = 0; ct < 4; ++ct) {
#pragma unroll
        for (int kk = 0; kk < 8; ++kk) {
            const float* p = w_r + (size_t)(s0 + ct * 16 + l15) * SD + (k0 + kk * 32 + lq * 8);
            bf8 f;
#pragma unroll
            for (int j = 0; j < 8; ++j) f[j] = (short)f2bf(p[j]);
            B1[ct][kk] = f;
        }
    }
    // ---- w_o slice: 16 rows -> full N=16 tile ----
    bf8 B2[8];
#pragma unroll
    for (int kk = 0; kk < 8; ++kk) {
        const float* p = w_o + (size_t)(o0 + l15) * SD + (k0 + kk * 32 + lq * 8);
        bf8 f;
#pragma unroll
        for (int j = 0; j < 8; ++j) f[j] = (short)f2bf(p[j]);
        B2[kk] = f;
    }

    // ---- per-thread h ownership: 4 consecutive states of one batch row ----
    const int hr = tid >> 4;            // batch-local row 0..15 (wave wid owns rows 4wid..4wid+3)
    const int hc = (tid & 15) * 4;      // state-local col base 0..60
    float4 br4  = *(const float4*)(b_r + s0 + hc);
    float4 hreg = *(const float4*)(h_init + (size_t)(batch0 + hr) * SD + s0 + hc);

    const int ct1 = hc >> 4;
    const int rg1 = hr & 3;
    const int ln1 = (hr >> 2) * 16 + (hc & 15);

    const int er  = tid >> 4;           // err element (row, col): one per thread
    const int ec  = tid & 15;
    const int rg2 = er & 3;
    const int ln2 = (er >> 2) * 16 + ec;
    const float bo = b_o[o0 + ec];

    const size_t t_off = (size_t)(batch0 + hr) * SD + s0 + hc;

    // ---- one-time XCD placement check (agent-scope, always correct) ----
    unsigned xcc = 0;
    asm volatile("s_getreg_b32 %0, hwreg(HW_REG_XCC_ID)" : "=s"(xcc));
    if (tid == 0)
        __hip_atomic_store(xarr + wi, xcc + 1u, __ATOMIC_RELAXED, __HIP_MEMORY_SCOPE_AGENT);
    __syncthreads();   // drains the xcc store (vmcnt) before the arrival add
    if (tid == 0) {
        unsigned old = __hip_atomic_fetch_add(scnt, 1u, __ATOMIC_RELAXED, __HIP_MEMORY_SCOPE_AGENT);
        if (old == 15u)
            __hip_atomic_store(sflag, 1u, __ATOMIC_RELAXED, __HIP_MEMORY_SCOPE_AGENT);
        while (__hip_atomic_load(sflag, __ATOMIC_RELAXED, __HIP_MEMORY_SCOPE_AGENT) < 1u)
            __builtin_amdgcn_s_sleep(1);
    }
    __syncthreads();
    if (tid < 16)
        sx[tid] = __hip_atomic_load(xarr + tid, __ATOMIC_RELAXED, __HIP_MEMORY_SCOPE_AGENT);
    __syncthreads();
    bool fastpath = true;
    for (int j = 1; j < 16; ++j) fastpath &= (sx[j] == sx[0]);

    // ---- per-wave barrier primitives (agent scope, placement-independent) ----
    // wait: lanes 0..15 each poll one producer-wave flag; wave iterates
    // (exec-masked) until all pass; s_sleep throttles (r8-proven cadence).
    auto wave_wait = [&](unsigned target) {
        if (lane < 16) {
            while (__hip_atomic_load(pollp, __ATOMIC_RELAXED, __HIP_MEMORY_SCOPE_AGENT) < target)
                __builtin_amdgcn_s_sleep(1);
        }
    };
    // publish: vmcnt is per-wave -> drains THIS wave's t-stores (rows
    // 4wid..4wid+3, all 64 cols) to L2/coherence pt before lane0 flags.
    auto wave_publish = [&](unsigned val) {
        asm volatile("s_waitcnt vmcnt(0)" ::: "memory");
        if (lane == 0)
            __hip_atomic_store(myflag, val, __ATOMIC_RELAXED, __HIP_MEMORY_SCOPE_AGENT);
    };

    // ================= main body, data path specialized on FAST =================
    auto body = [&](auto FC) {
        constexpr bool FAST = decltype(FC)::value;

        auto t_store = [&](unsigned short* p, float a, float b, float c, float d) {
            unsigned long long v = (unsigned long long)f2bf(a)
                                 | ((unsigned long long)f2bf(b) << 16)
                                 | ((unsigned long long)f2bf(c) << 32)
                                 | ((unsigned long long)f2bf(d) << 48);
            if constexpr (FAST) {             // write-through L1 -> lands in XCD L2 (r6-verified)
                *(unsigned long long*)p = v;
            } else {
                __hip_atomic_store((unsigned long long*)p, v, __ATOMIC_RELAXED, __HIP_MEMORY_SCOPE_AGENT);
            }
        };

        // load 8 A fragments; FAST: sc0 loads serve from XCD L2 (r6-verified)
        auto loadA = [&](bf8 (&A)[8], const unsigned short* ap) {
            if constexpr (FAST) {
                u32x4 r[8];
#pragma unroll
                for (int kk = 0; kk < 8; ++kk)
                    asm volatile("global_load_dwordx4 %0, %1, off sc0"
                                 : "=v"(r[kk]) : "v"((const void*)(ap + kk * 32)));
                asm volatile("s_waitcnt vmcnt(0)" ::: "memory");
                __builtin_amdgcn_sched_barrier(0);   // rule #18: keep MFMAs after the wait
#pragma unroll
                for (int kk = 0; kk < 8; ++kk) {
                    BF16x8 u; u.u = r[kk]; A[kk] = u.v;
                }
            } else {
#pragma unroll
                for (int kk = 0; kk < 8; ++kk) A[kk] = t_load16_agent(ap + kk * 32);
            }
        };

        bf8 A[8];  // A fragments of current t tile (t_i serves gemm1 AND err_{i-1})

        // ---- t0 = tanh(h_init) into buffer 0 ----
        t_store(tbase + t_off, fast_tanh(hreg.x), fast_tanh(hreg.y),
                               fast_tanh(hreg.z), fast_tanh(hreg.w));
        wave_publish(1u);

        for (int i = 0; i < SEQ; ++i) {
            const int par = i & 1;
            const bool do2 = (i >= 1);
            size_t oidx = 0; float xv = 0.f;
            if (do2) {   // x prefetch: issued before the poll, consumed after it
                oidx = (size_t)(i - 1) * (BATCH * OD) + (size_t)(batch0 + er) * OD + o0 + ec;
                xv = x[oidx];
            }

            wave_wait((unsigned)(i + 1));    // my 16 producer waves stored t_i

            const unsigned short* tb = tbase + (size_t)(i % 3) * (BATCH * SD);
            unsigned short* tn = tbase + (size_t)((i + 1) % 3) * (BATCH * SD);
            const unsigned short* ap = tb + (size_t)(batch0 + l15) * SD + k0 + lq * 8;
            loadA(A, ap);

            // ---- gemm2 front: err_{i-1} = t_i @ w_o^T + b_o - x_{i-1} ----
            if (do2) {
                f32x4 c = {0.f, 0.f, 0.f, 0.f};
#pragma unroll
                for (int kk = 0; kk < 8; ++kk)
                    c = __builtin_amdgcn_mfma_f32_16x16x32_bf16(A[kk], B2[kk], c, 0, 0, 0);
#pragma unroll
                for (int q = 0; q < 4; ++q) red2[par][wid][q][lane] = c[q];
            }

            // ---- recurrent GEMM: C[16x64] per wave over its K slice ----
            f32x4 acc0 = {0.f,0.f,0.f,0.f}, acc1 = {0.f,0.f,0.f,0.f};
            f32x4 acc2 = {0.f,0.f,0.f,0.f}, acc3 = {0.f,0.f,0.f,0.f};
#pragma unroll
            for (int kk = 0; kk < 8; ++kk) {
                acc0 = __builtin_amdgcn_mfma_f32_16x16x32_bf16(A[kk], B1[0][kk], acc0, 0, 0, 0);
                acc1 = __builtin_amdgcn_mfma_f32_16x16x32_bf16(A[kk], B1[1][kk], acc1, 0, 0, 0);
                acc2 = __builtin_amdgcn_mfma_f32_16x16x32_bf16(A[kk], B1[2][kk], acc2, 0, 0, 0);
                acc3 = __builtin_amdgcn_mfma_f32_16x16x32_bf16(A[kk], B1[3][kk], acc3, 0, 0, 0);
            }
#pragma unroll
            for (int q = 0; q < 4; ++q) {
                red1[par][wid][0][q][lane] = acc0[q];
                red1[par][wid][1][q][lane] = acc1[q];
                red1[par][wid][2][q][lane] = acc2[q];
                red1[par][wid][3][q][lane] = acc3[q];
            }
            __syncthreads();   // the ONE barrier: orders red1+red2, unions flag views

            // ---- K-reduction + leaky h update + tanh + publish ----
            float4 p0 = *(const float4*)&red1[par][0][ct1][rg1][ln1];
            float4 p1 = *(const float4*)&red1[par][1][ct1][rg1][ln1];
            float4 p2 = *(const float4*)&red1[par][2][ct1][rg1][ln1];
            float4 p3 = *(const float4*)&red1[par][3][ct1][rg1][ln1];
            hreg.x = 0.9f * hreg.x + 0.1f * (p0.x + p1.x + p2.x + p3.x + br4.x);
            hreg.y = 0.9f * hreg.y + 0.1f * (p0.y + p1.y + p2.y + p3.y + br4.y);
            hreg.z = 0.9f * hreg.z + 0.1f * (p0.z + p1.z + p2.z + p3.z + br4.z);
            hreg.w = 0.9f * hreg.w + 0.1f * (p0.w + p1.w + p2.w + p3.w + br4.w);
            t_store(tn + t_off, fast_tanh(hreg.x), fast_tanh(hreg.y),
                                fast_tanh(hreg.z), fast_tanh(hreg.w));
            wave_publish((unsigned)(i + 2));   // wave vmcnt drain + 1 agent store

            // ---- gemm2 back: off the critical path, after publish ----
            if (do2) {
                float sum = red2[par][0][rg2][ln2] + red2[par][1][rg2][ln2]
                          + red2[par][2][rg2][ln2] + red2[par][3][rg2][ln2];
                out[oidx] = sum + bo - xv;
            }
        }

        // ---- epilogue: err_{511} from t_512 ----
        {
            size_t oidx = (size_t)(SEQ - 1) * (BATCH * OD) + (size_t)(batch0 + er) * OD + o0 + ec;
            float xv = x[oidx];
            wave_wait((unsigned)(SEQ + 1));   // producers stored t_512
            const unsigned short* tb = tbase + (size_t)(SEQ % 3) * (BATCH * SD);
            const unsigned short* ap = tb + (size_t)(batch0 + l15) * SD + k0 + lq * 8;
            loadA(A, ap);
            f32x4 c = {0.f, 0.f, 0.f, 0.f};
#pragma unroll
            for (int kk = 0; kk < 8; ++kk)
                c = __builtin_amdgcn_mfma_f32_16x16x32_bf16(A[kk], B2[kk], c, 0, 0, 0);
#pragma unroll
            for (int q = 0; q < 4; ++q) red2[0][wid][q][lane] = c[q];   // red2[0]: last use ended pre-sync_511
            __syncthreads();
            float sum = red2[0][0][rg2][ln2] + red2[0][1][rg2][ln2]
                      + red2[0][2][rg2][ln2] + red2[0][3][rg2][ln2];
            out[oidx] = sum + bo - xv;
        }
    };

    if (fastpath) {
        body(BoolC<true>{});
    } else {
        body(BoolC<false>{});
    }
}

extern "C" void kernel_launch(void* const* d_in, const int* in_sizes, int n_in,
                              void* d_out, int out_size, void* d_ws, size_t ws_size,
                              hipStream_t stream)
{
    const float* x      = (const float*)d_in[0];
    const float* h_init = (const float*)d_in[1];
    const float* w_r    = (const float*)d_in[2];
    const float* b_r    = (const float*)d_in[3];
    const float* w_o    = (const float*)d_in[4];
    const float* b_o    = (const float*)d_in[5];
    float* out = (float*)d_out;

    // ws layout: [0,64K) wave flags, [64K,68K) startup, [68K, +3*512K) t triple buffer
    hipMemsetAsync(d_ws, 0, 69632, stream);
    rnn_persistent<<<dim3(256), dim3(256), 0, stream>>>(
        x, h_init, w_r, b_r, w_o, b_o, out, (unsigned char*)d_ws);
}